// Round 1
// baseline (1256.132 us; speedup 1.0000x reference)
//
#include <hip/hip_runtime.h>
#include <hip/hip_bf16.h>

#define B_N 16
#define U_N 2048
#define S_N 512
#define D_N 128
#define NEGV (-1000000000.0f)
#define INV_SQRT_D 0.08838834764831845f

// ---------- helpers ----------
__device__ __forceinline__ unsigned monof(float v) {
    unsigned b = __float_as_uint(v);
    return (b & 0x80000000u) ? ~b : (b | 0x80000000u);
}
__device__ __forceinline__ float unmonof(unsigned m) {
    unsigned b = (m & 0x80000000u) ? (m & 0x7fffffffu) : ~m;
    return __uint_as_float(b);
}

// ---------- init: zero state, pack needs/caps/fd masks ----------
__global__ void init_state(const float* __restrict__ servers, const float* __restrict__ users,
                           const int* __restrict__ fd_onehot,
                           unsigned* allocT, unsigned* allocU, unsigned* rcArr, unsigned* seenArr,
                           unsigned* seen_gain, float* logp, unsigned long long* ukey,
                           float* capA, float* invA, unsigned* fdm, float* nds,
                           int* go, unsigned* any_valid, unsigned* done_cnt, int* need_count) {
    int i = blockIdx.x * 256 + threadIdx.x;  // grid 2048 blocks -> 524288 threads
    if (i < 524288) { allocT[i] = 0u; allocU[i] = 0u; }
    if (i < B_N * U_N) {
        rcArr[i] = 0u; seenArr[i] = 0u; seen_gain[i] = 0u; logp[i] = 0.f; ukey[i] = 0ULL;
        const float* up = users + (size_t)i * 6;
        nds[i * 4 + 0] = up[2]; nds[i * 4 + 1] = up[3];
        nds[i * 4 + 2] = up[4]; nds[i * 4 + 3] = up[5];
    }
    if (i < B_N * S_N) {
        const float* sp = servers + (size_t)i * 7;
        float4 c = make_float4(sp[3], sp[4], sp[5], sp[6]);
        ((float4*)capA)[i] = c;
        ((float4*)invA)[i] = make_float4(1.f / fmaxf(c.x, 1e-6f), 1.f / fmaxf(c.y, 1e-6f),
                                         1.f / fmaxf(c.z, 1e-6f), 1.f / fmaxf(c.w, 1e-6f));
        unsigned w = 0u;
        const int* fp = fd_onehot + (size_t)i * 32;
        #pragma unroll
        for (int f = 0; f < 32; ++f) w |= (fp[f] != 0 ? 1u : 0u) << f;
        fdm[i] = w;
    }
    if (i < 16) { any_valid[i] = 0u; done_cnt[i] = 0u; go[i + 1] = 0; }
    if (i == 0) { go[0] = 1; *need_count = B_N * U_N; }
}

// ---------- pack connect (B,U,S) int32 -> (B,S,U/32) bits ----------
__global__ void pack_connect(const int* __restrict__ connect, unsigned* __restrict__ connT) {
    int b = blockIdx.z;
    int u0 = blockIdx.y * 32;
    int s = blockIdx.x * 256 + threadIdx.x;
    unsigned w = 0u;
    for (int r = 0; r < 32; ++r) {
        int v = connect[((size_t)(b * U_N + u0 + r)) * S_N + s];
        w |= (v != 0 ? 1u : 0u) << r;
    }
    connT[(b * S_N + s) * 64 + (u0 >> 5)] = w;
}

// ---------- generic fp32 GEMM: C[z][m][n] = scale * sum_k (A[z][m][k](+abias[k])) * B[(z)][n][k]
template <bool BSHARED, bool ABIAS>
__global__ __launch_bounds__(256) void gemm_nt(const float* __restrict__ A, const float* __restrict__ Bm,
                                               const float* __restrict__ abias, float* __restrict__ C,
                                               int M, int N, int K, float scale) {
    __shared__ float As[16][68];
    __shared__ float Bs[16][68];
    int z = blockIdx.z;
    const float* Ab = A + (size_t)z * M * K;
    const float* Bb = BSHARED ? Bm : (Bm + (size_t)z * N * K);
    float* Cb = C + (size_t)z * M * N;
    int m0 = blockIdx.x * 64, n0 = blockIdx.y * 64;
    int tid = threadIdx.x;
    int tx = tid & 15, ty = tid >> 4;
    int lrow = tid >> 2, lk = (tid & 3) * 4;
    float acc[4][4] = {};
    for (int k0 = 0; k0 < K; k0 += 16) {
        float4 av = *(const float4*)(Ab + (size_t)(m0 + lrow) * K + k0 + lk);
        float4 bv = *(const float4*)(Bb + (size_t)(n0 + lrow) * K + k0 + lk);
        if (ABIAS) {
            av.x += abias[k0 + lk]; av.y += abias[k0 + lk + 1];
            av.z += abias[k0 + lk + 2]; av.w += abias[k0 + lk + 3];
        }
        __syncthreads();
        As[lk + 0][lrow] = av.x; As[lk + 1][lrow] = av.y; As[lk + 2][lrow] = av.z; As[lk + 3][lrow] = av.w;
        Bs[lk + 0][lrow] = bv.x; Bs[lk + 1][lrow] = bv.y; Bs[lk + 2][lrow] = bv.z; Bs[lk + 3][lrow] = bv.w;
        __syncthreads();
        #pragma unroll
        for (int kk = 0; kk < 16; ++kk) {
            float4 a = *(const float4*)&As[kk][ty * 4];
            float4 bq = *(const float4*)&Bs[kk][tx * 4];
            float ar[4] = {a.x, a.y, a.z, a.w}, br[4] = {bq.x, bq.y, bq.z, bq.w};
            #pragma unroll
            for (int ii = 0; ii < 4; ++ii)
                #pragma unroll
                for (int jj = 0; jj < 4; ++jj) acc[ii][jj] += ar[ii] * br[jj];
        }
    }
    #pragma unroll
    for (int ii = 0; ii < 4; ++ii) {
        float4 o = make_float4(acc[ii][0] * scale, acc[ii][1] * scale,
                               acc[ii][2] * scale, acc[ii][3] * scale);
        *(float4*)(Cb + (size_t)(m0 + ty * 4 + ii) * N + n0 + tx * 4) = o;
    }
}

// ---------- M2[d][c] = inv_sqrt_d * sum_e ptr_k_w[d,e]*state_proj_w[e,c] ----------
__global__ void m2_kernel(const float* __restrict__ kw, const float* __restrict__ spw, float* __restrict__ M2) {
    int t = threadIdx.x;
    if (t < 512) {
        int d = t >> 2, c = t & 3;
        float acc = 0.f;
        for (int e = 0; e < 128; ++e) acc += kw[d * 128 + e] * spw[e * 4 + c];
        M2[t] = acc * INV_SQRT_D;
    }
}

// ---------- qm[b,u,c] = sum_d q[b,u,d]*M2[d,c] ----------
__global__ void qm_kernel(const float* __restrict__ q, const float* __restrict__ M2, float* __restrict__ qm) {
    __shared__ float qs[64][129];
    __shared__ float m2s[512];
    int b = blockIdx.y, u0 = blockIdx.x * 64;
    int t = threadIdx.x;
    for (int i = t; i < 512; i += 256) m2s[i] = M2[i];
    #pragma unroll
    for (int it = 0; it < 8; ++it) {
        int f4 = t + 256 * it;
        int row = f4 >> 5;
        int col = (f4 & 31) * 4;
        float4 v = *(const float4*)(q + ((size_t)(b * U_N + u0 + row)) * D_N + col);
        qs[row][col] = v.x; qs[row][col + 1] = v.y; qs[row][col + 2] = v.z; qs[row][col + 3] = v.w;
    }
    __syncthreads();
    int ul = t >> 2, c = t & 3;
    float acc = 0.f;
    for (int d = 0; d < 128; ++d) acc += qs[ul][d] * m2s[d * 4 + c];
    qm[((size_t)(b * U_N + u0 + ul)) * 4 + c] = acc;
}

// ---------- per-iteration scoring: one block handles (b, 4 servers), scans all u ----------
__global__ __launch_bounds__(256) void iter_score(
    const float* __restrict__ baseT, const float* __restrict__ qm4,
    const float* __restrict__ nds, const unsigned* __restrict__ connT,
    const unsigned* __restrict__ allocT, const unsigned* __restrict__ rcArr,
    const unsigned* __restrict__ seenArr, const unsigned* __restrict__ fdm_,
    const float* __restrict__ capA, const float* __restrict__ invA,
    const float* __restrict__ usw, const float* __restrict__ sbp, const float* __restrict__ fdbp,
    float* __restrict__ logp_prop, unsigned long long* __restrict__ ukey,
    unsigned* __restrict__ seen_gain, int* __restrict__ go,
    unsigned* __restrict__ any_valid, unsigned* __restrict__ done_cnt,
    const int* __restrict__ need_count, int iter) {
    const int tid = threadIdx.x;
    const int b = blockIdx.x >> 7;
    const int s0 = (blockIdx.x & 127) * 4;
    if (go[iter] == 0) {  // frozen: nothing can change; still participate in go[iter+1]
        if (tid == 0) {
            __threadfence();
            if (atomicAdd(&done_cnt[iter], 1u) == (unsigned)(gridDim.x - 1)) go[iter + 1] = 0;
        }
        return;
    }
    float w0 = usw[0], w1 = usw[1], w2 = usw[2];
    float sb = sbp[0], fdb = fdbp[0];
    float ub[4];
    #pragma unroll
    for (int r = 0; r < 4; ++r)
        ub[r] = sb + w0 * (r * (1.0f / 3.0f)) + w1 * ((3 - r) * (1.0f / 3.0f)) + (r == 2 ? w2 : 0.0f);
    float4 capv[4], crv[4]; unsigned fdm[4];
    #pragma unroll
    for (int j = 0; j < 4; ++j) {
        int bs = b * S_N + s0 + j;
        capv[j] = ((const float4*)capA)[bs];
        float4 iv = ((const float4*)invA)[bs];
        crv[j] = make_float4(capv[j].x * iv.x, capv[j].y * iv.y, capv[j].z * iv.z, capv[j].w * iv.w);
        fdm[j] = fdm_[bs];
    }
    float cand[2][4][4];
    unsigned long long key[4] = {0ULL, 0ULL, 0ULL, 0ULL};
    #pragma unroll
    for (int g = 0; g < 2; ++g) {
        int u = 4 * tid + 1024 * g;
        uint4 rc4 = *(const uint4*)(rcArr + b * U_N + u);
        uint4 sn4 = *(const uint4*)(seenArr + b * U_N + u);
        float4 qmv[4], ndv[4];
        #pragma unroll
        for (int x = 0; x < 4; ++x) {
            qmv[x] = ((const float4*)qm4)[b * U_N + u + x];
            ndv[x] = ((const float4*)nds)[b * U_N + u + x];
        }
        unsigned rr[4] = {rc4.x, rc4.y, rc4.z, rc4.w};
        unsigned ss[4] = {sn4.x, sn4.y, sn4.z, sn4.w};
        #pragma unroll
        for (int j = 0; j < 4; ++j) {
            int bs = b * S_N + s0 + j;
            float4 bl = *(const float4*)(baseT + (size_t)bs * U_N + u);
            float blv[4] = {bl.x, bl.y, bl.z, bl.w};
            unsigned cw = connT[bs * 64 + (u >> 5)];
            unsigned aw = allocT[bs * 64 + (u >> 5)];
            #pragma unroll
            for (int x = 0; x < 4; ++x) {
                int uu = u + x;
                bool okbits = ((cw >> (uu & 31)) & 1u) && !((aw >> (uu & 31)) & 1u);
                bool fulfill = (capv[j].x >= ndv[x].x) && (capv[j].y >= ndv[x].y) &&
                               (capv[j].z >= ndv[x].z) && (capv[j].w >= ndv[x].w);
                bool elig = okbits && fulfill && (rr[x] < 3u);
                float lg = blv[x] + qmv[x].x * crv[j].x + qmv[x].y * crv[j].y +
                           qmv[x].z * crv[j].z + qmv[x].w * crv[j].w + ub[rr[x] & 3u] +
                           (((ss[x] & fdm[j]) == 0u) ? fdb : 0.0f);
                float c = elig ? lg : NEGV;
                cand[g][j][x] = c;
                unsigned long long k = ((unsigned long long)monof(c) << 32) | (unsigned)(~(unsigned)uu);
                key[j] = key[j] > k ? key[j] : k;
            }
        }
    }
    __shared__ unsigned long long redk[4];
    __shared__ float redS[4];
    #pragma unroll
    for (int j = 0; j < 4; ++j) {
        unsigned long long k = key[j];
        #pragma unroll
        for (int m = 1; m < 64; m <<= 1) {
            unsigned long long o = __shfl_xor(k, m, 64);
            k = o > k ? o : k;
        }
        if ((tid & 63) == 0) redk[tid >> 6] = k;
        __syncthreads();
        unsigned long long bk = redk[0];
        bk = redk[1] > bk ? redk[1] : bk;
        bk = redk[2] > bk ? redk[2] : bk;
        bk = redk[3] > bk ? redk[3] : bk;
        float mx = unmonof((unsigned)(bk >> 32));
        float lsum = 0.f;
        #pragma unroll
        for (int g = 0; g < 2; ++g)
            #pragma unroll
            for (int x = 0; x < 4; ++x) lsum += __expf(cand[g][j][x] - mx);
        #pragma unroll
        for (int mm = 1; mm < 64; mm <<= 1) lsum += __shfl_xor(lsum, mm, 64);
        if ((tid & 63) == 0) redS[tid >> 6] = lsum;
        __syncthreads();
        if (tid == 0) {
            bool valid = mx > -5.0e8f;  // any eligible user for this server
            if (valid) {
                float tot = redS[0] + redS[1] + redS[2] + redS[3];
                int bs = b * S_N + s0 + j;
                logp_prop[bs] = -__logf(tot);
                unsigned pu = ~(unsigned)bk;  // winning user (first-index on ties)
                unsigned long long pk =
                    ((unsigned long long)monof(mx) << 32) | (unsigned)(~(unsigned)(s0 + j));
                atomicMax(&ukey[b * U_N + pu], pk);
                atomicOr(&seen_gain[b * U_N + pu], fdm[j]);
                atomicOr(&any_valid[iter], 1u);
            }
        }
        __syncthreads();
    }
    if (tid == 0) {
        __threadfence();
        if (atomicAdd(&done_cnt[iter], 1u) == (unsigned)(gridDim.x - 1)) {
            unsigned av = atomicOr(&any_valid[iter], 0u);
            go[iter + 1] = (av != 0u) && (*need_count > 0) ? 1 : 0;
        }
    }
}

// ---------- per-iteration apply: each user accepts its best proposer ----------
__global__ void iter_apply(const float* __restrict__ nds, const float* __restrict__ logp_prop,
                           unsigned long long* __restrict__ ukey, unsigned* __restrict__ seen_gain,
                           unsigned* __restrict__ allocT, unsigned* __restrict__ allocU,
                           unsigned* __restrict__ rcArr, unsigned* __restrict__ seenArr,
                           float* __restrict__ capA, float* __restrict__ logp,
                           const int* __restrict__ go, int* __restrict__ need_count, int iter) {
    int i = blockIdx.x * 256 + threadIdx.x;  // B*U
    unsigned long long key = ukey[i];
    if (key == 0ULL) return;
    if (go[iter + 1] != 0) {
        int b = i >> 11, u = i & 2047;
        unsigned s = ~(unsigned)key;  // decode server
        int bs = b * S_N + (int)s;
        allocT[bs * 64 + (u >> 5)] |= 1u << (u & 31);
        allocU[i * 16 + ((int)s >> 5)] |= 1u << (s & 31);
        float4 nd = ((const float4*)nds)[i];
        float4 cv = ((float4*)capA)[bs];
        cv.x = fmaxf(cv.x - nd.x, 0.f); cv.y = fmaxf(cv.y - nd.y, 0.f);
        cv.z = fmaxf(cv.z - nd.z, 0.f); cv.w = fmaxf(cv.w - nd.w, 0.f);
        ((float4*)capA)[bs] = cv;
        unsigned r = rcArr[i] + 1u; rcArr[i] = r;
        if (r == 3u) atomicSub(need_count, 1);
        logp[i] += logp_prop[bs];
        seenArr[i] |= seen_gain[i];
    }
    ukey[i] = 0ULL;
    seen_gain[i] = 0u;
}

// ---------- finalize ----------
__global__ void finalize_logp(const float* __restrict__ logp, float* __restrict__ out) {
    int b = blockIdx.x, t = threadIdx.x;
    float s = 0.f;
    for (int u = t; u < U_N; u += 256) s += logp[b * U_N + u];
    #pragma unroll
    for (int m = 1; m < 64; m <<= 1) s += __shfl_xor(s, m, 64);
    __shared__ float r[4];
    if ((t & 63) == 0) r[t >> 6] = s;
    __syncthreads();
    if (t == 0) out[b] = r[0] + r[1] + r[2] + r[3];
}

__global__ void finalize_alloc(const unsigned* __restrict__ allocU, float* __restrict__ out) {
    int idx = blockIdx.x * 256 + threadIdx.x;  // B*U*S/4
    int bu = idx >> 7;
    int s4 = (idx & 127) * 4;
    unsigned w = allocU[bu * 16 + (s4 >> 5)];
    float4 o;
    o.x = ((w >> ((s4 + 0) & 31)) & 1u) ? 1.f : 0.f;
    o.y = ((w >> ((s4 + 1) & 31)) & 1u) ? 1.f : 0.f;
    o.z = ((w >> ((s4 + 2) & 31)) & 1u) ? 1.f : 0.f;
    o.w = ((w >> ((s4 + 3) & 31)) & 1u) ? 1.f : 0.f;
    *(float4*)(out + 16 + (size_t)bu * S_N + s4) = o;
}

__global__ void finalize_cap(const float* __restrict__ capA, float* __restrict__ out) {
    int i = blockIdx.x * 256 + threadIdx.x;
    if (i < B_N * S_N * 4) out[16 + (size_t)B_N * U_N * S_N + i] = capA[i];
}

extern "C" void kernel_launch(void* const* d_in, const int* in_sizes, int n_in,
                              void* d_out, int out_size, void* d_ws, size_t ws_size,
                              hipStream_t stream) {
    const float* user_enc = (const float*)d_in[0];
    const float* server_enc = (const float*)d_in[1];
    const float* users = (const float*)d_in[2];
    const float* servers = (const float*)d_in[3];
    const int* connect = (const int*)d_in[4];
    const int* fd_onehot = (const int*)d_in[5];
    const float* state_proj_w = (const float*)d_in[6];
    const float* state_proj_b = (const float*)d_in[7];
    const float* fd_bias = (const float*)d_in[8];
    const float* ptr_q_w = (const float*)d_in[9];
    const float* ptr_k_w = (const float*)d_in[10];
    const float* user_state_w = (const float*)d_in[11];
    const float* score_bias = (const float*)d_in[12];
    float* out = (float*)d_out;

    char* w = (char*)d_ws;
    float* baseT = (float*)(w + 0);                        // (B,S,U) 67108864 B
    float* q = (float*)(w + 67108864);                     // (B,U,D) 16777216 B
    float* base_k = (float*)(w + 83886080);                // (B,S,D) 4194304 B
    float* qm = (float*)(w + 88080384);                    // (B,U,4) 524288 B
    unsigned* connT = (unsigned*)(w + 88604672);           // (B,S,64) 2097152 B
    unsigned* allocT = (unsigned*)(w + 90701824);          // (B,S,64) 2097152 B
    unsigned* allocU = (unsigned*)(w + 92798976);          // (B,U,16) 2097152 B
    float* nds = (float*)(w + 94896128);                   // (B,U,4) 524288 B
    unsigned* fdm = (unsigned*)(w + 95420416);             // (B,S) 32768 B
    float* capA = (float*)(w + 95453184);                  // (B,S,4) 131072 B
    float* invA = (float*)(w + 95584256);                  // (B,S,4) 131072 B
    unsigned* rcArr = (unsigned*)(w + 95715328);           // (B,U) 131072 B
    unsigned* seenArr = (unsigned*)(w + 95846400);         // (B,U) 131072 B
    unsigned* seen_gain = (unsigned*)(w + 95977472);       // (B,U) 131072 B
    float* logp = (float*)(w + 96108544);                  // (B,U) 131072 B
    unsigned long long* ukey = (unsigned long long*)(w + 96239616);  // (B,U) 262144 B
    float* logp_prop = (float*)(w + 96501760);             // (B,S) 32768 B
    float* M2 = (float*)(w + 96534528);                    // (D,4) 2048 B
    int* go = (int*)(w + 96536576);                        // 17 ints
    unsigned* any_valid = (unsigned*)(w + 96536576 + 128); // 16
    unsigned* done_cnt = (unsigned*)(w + 96536576 + 192);  // 16
    int* need_count = (int*)(w + 96536576 + 256);

    init_state<<<2048, 256, 0, stream>>>(servers, users, fd_onehot, allocT, allocU, rcArr, seenArr,
                                         seen_gain, logp, ukey, capA, invA, fdm, nds,
                                         go, any_valid, done_cnt, need_count);
    pack_connect<<<dim3(2, 64, 16), 256, 0, stream>>>(connect, connT);
    // base_k = inv_sqrt_d * (server_enc + spb) @ ptr_k_w^T
    gemm_nt<true, true><<<dim3(8, 2, 16), 256, 0, stream>>>(server_enc, ptr_k_w, state_proj_b,
                                                            base_k, S_N, D_N, D_N, INV_SQRT_D);
    // q = user_enc @ ptr_q_w^T
    gemm_nt<true, false><<<dim3(32, 2, 16), 256, 0, stream>>>(user_enc, ptr_q_w, nullptr,
                                                              q, U_N, D_N, D_N, 1.0f);
    m2_kernel<<<1, 512, 0, stream>>>(ptr_k_w, state_proj_w, M2);
    qm_kernel<<<dim3(32, 16), 256, 0, stream>>>(q, M2, qm);
    // baseT[b][s][u] = base_k[b][s] . q[b][u]   (scale already folded into base_k)
    gemm_nt<false, false><<<dim3(8, 32, 16), 256, 0, stream>>>(base_k, q, nullptr,
                                                               baseT, S_N, U_N, D_N, 1.0f);
    for (int it = 0; it < 16; ++it) {
        iter_score<<<2048, 256, 0, stream>>>(baseT, qm, nds, connT, allocT, rcArr, seenArr, fdm,
                                             capA, invA, user_state_w, score_bias, fd_bias,
                                             logp_prop, ukey, seen_gain, go, any_valid, done_cnt,
                                             need_count, it);
        iter_apply<<<128, 256, 0, stream>>>(nds, logp_prop, ukey, seen_gain, allocT, allocU,
                                            rcArr, seenArr, capA, logp, go, need_count, it);
    }
    finalize_logp<<<16, 256, 0, stream>>>(logp, out);
    finalize_alloc<<<16384, 256, 0, stream>>>(allocU, out);
    finalize_cap<<<128, 256, 0, stream>>>(capA, out);
}

// Round 2
// 572.902 us; speedup vs baseline: 2.1926x; 2.1926x over previous
//
#include <hip/hip_runtime.h>
#include <hip/hip_bf16.h>

#define B_N 16
#define U_N 2048
#define S_N 512
#define D_N 128
#define NEGV (-1000000000.0f)
#define INV_SQRT_D 0.08838834764831845f

typedef unsigned long long ull;

// ---------- helpers ----------
__device__ __forceinline__ unsigned monof(float v) {
    unsigned b = __float_as_uint(v);
    return (b & 0x80000000u) ? ~b : (b | 0x80000000u);
}
__device__ __forceinline__ float unmonof(unsigned m) {
    unsigned b = (m & 0x80000000u) ? (m & 0x7fffffffu) : ~m;
    return __uint_as_float(b);
}

// ---------- init: zero state, pack needs/caps/fd masks ----------
__global__ void init_state(const float* __restrict__ servers, const float* __restrict__ users,
                           const int* __restrict__ fd_onehot,
                           unsigned* allocU, uint4* alloc3, unsigned* rcArr, unsigned* seenArr,
                           unsigned* seen_gain, float* logp, ull* ukey,
                           float* capA, float* invA, unsigned* fdm, float* nds,
                           int* go, unsigned* any_valid, unsigned* done_cnt, int* need_count) {
    int i = blockIdx.x * 256 + threadIdx.x;  // 2048 blocks -> 524288 threads
    if (i < B_N * U_N * 16) allocU[i] = 0u;
    if (i < B_N * U_N) {
        rcArr[i] = 0u; seenArr[i] = 0u; seen_gain[i] = 0u; logp[i] = 0.f; ukey[i] = 0ULL;
        alloc3[i] = make_uint4(0xFFFFFFFFu, 0xFFFFFFFFu, 0xFFFFFFFFu, 0xFFFFFFFFu);
        const float* up = users + (size_t)i * 6;
        nds[i * 4 + 0] = up[2]; nds[i * 4 + 1] = up[3];
        nds[i * 4 + 2] = up[4]; nds[i * 4 + 3] = up[5];
    }
    if (i < B_N * S_N) {
        const float* sp = servers + (size_t)i * 7;
        float4 c = make_float4(sp[3], sp[4], sp[5], sp[6]);
        ((float4*)capA)[i] = c;
        ((float4*)invA)[i] = make_float4(1.f / fmaxf(c.x, 1e-6f), 1.f / fmaxf(c.y, 1e-6f),
                                         1.f / fmaxf(c.z, 1e-6f), 1.f / fmaxf(c.w, 1e-6f));
        unsigned w = 0u;
        const int* fp = fd_onehot + (size_t)i * 32;
        #pragma unroll
        for (int f = 0; f < 32; ++f) w |= (fp[f] != 0 ? 1u : 0u) << f;
        fdm[i] = w;
    }
    if (i < 16) { any_valid[i] = 0u; done_cnt[i] = 0u; go[i + 1] = 0; }
    if (i == 0) { go[0] = 1; *need_count = B_N * U_N; }
}

// ---------- pack connect (B,U,S) int32 -> (B,U,S-bits): ballot per wave ----------
__global__ void pack_connect(const int* __restrict__ connect, ull* __restrict__ connU) {
    int i = blockIdx.x * 4 + (threadIdx.x >> 6);  // row index in [0, B*U)
    int lane = threadIdx.x & 63;
    const int* row = connect + (size_t)i * S_N;
    #pragma unroll
    for (int c = 0; c < 8; ++c) {
        ull m = __ballot(row[c * 64 + lane] != 0);
        if (lane == 0) connU[(size_t)i * 8 + c] = m;
    }
}

// ---------- generic fp32 GEMM: C[z][m][n] = scale * sum_k (A[z][m][k](+abias[k])) * B[(z)][n][k]
template <bool BSHARED, bool ABIAS>
__global__ __launch_bounds__(256) void gemm_nt(const float* __restrict__ A, const float* __restrict__ Bm,
                                               const float* __restrict__ abias, float* __restrict__ C,
                                               int M, int N, int K, float scale) {
    __shared__ float As[16][68];
    __shared__ float Bs[16][68];
    int z = blockIdx.z;
    const float* Ab = A + (size_t)z * M * K;
    const float* Bb = BSHARED ? Bm : (Bm + (size_t)z * N * K);
    float* Cb = C + (size_t)z * M * N;
    int m0 = blockIdx.x * 64, n0 = blockIdx.y * 64;
    int tid = threadIdx.x;
    int tx = tid & 15, ty = tid >> 4;
    int lrow = tid >> 2, lk = (tid & 3) * 4;
    float acc[4][4] = {};
    for (int k0 = 0; k0 < K; k0 += 16) {
        float4 av = *(const float4*)(Ab + (size_t)(m0 + lrow) * K + k0 + lk);
        float4 bv = *(const float4*)(Bb + (size_t)(n0 + lrow) * K + k0 + lk);
        if (ABIAS) {
            av.x += abias[k0 + lk]; av.y += abias[k0 + lk + 1];
            av.z += abias[k0 + lk + 2]; av.w += abias[k0 + lk + 3];
        }
        __syncthreads();
        As[lk + 0][lrow] = av.x; As[lk + 1][lrow] = av.y; As[lk + 2][lrow] = av.z; As[lk + 3][lrow] = av.w;
        Bs[lk + 0][lrow] = bv.x; Bs[lk + 1][lrow] = bv.y; Bs[lk + 2][lrow] = bv.z; Bs[lk + 3][lrow] = bv.w;
        __syncthreads();
        #pragma unroll
        for (int kk = 0; kk < 16; ++kk) {
            float4 a = *(const float4*)&As[kk][ty * 4];
            float4 bq = *(const float4*)&Bs[kk][tx * 4];
            float ar[4] = {a.x, a.y, a.z, a.w}, br[4] = {bq.x, bq.y, bq.z, bq.w};
            #pragma unroll
            for (int ii = 0; ii < 4; ++ii)
                #pragma unroll
                for (int jj = 0; jj < 4; ++jj) acc[ii][jj] += ar[ii] * br[jj];
        }
    }
    #pragma unroll
    for (int ii = 0; ii < 4; ++ii) {
        float4 o = make_float4(acc[ii][0] * scale, acc[ii][1] * scale,
                               acc[ii][2] * scale, acc[ii][3] * scale);
        *(float4*)(Cb + (size_t)(m0 + ty * 4 + ii) * N + n0 + tx * 4) = o;
    }
}

// ---------- M2[d][c] = inv_sqrt_d * sum_e ptr_k_w[d,e]*state_proj_w[e,c] ----------
__global__ void m2_kernel(const float* __restrict__ kw, const float* __restrict__ spw, float* __restrict__ M2) {
    int t = threadIdx.x;
    if (t < 512) {
        int d = t >> 2, c = t & 3;
        float acc = 0.f;
        for (int e = 0; e < 128; ++e) acc += kw[d * 128 + e] * spw[e * 4 + c];
        M2[t] = acc * INV_SQRT_D;
    }
}

// ---------- qm[b,u,c] = sum_d q[b,u,d]*M2[d,c] ----------
__global__ void qm_kernel(const float* __restrict__ q, const float* __restrict__ M2, float* __restrict__ qm) {
    __shared__ float qs[64][129];
    __shared__ float m2s[512];
    int b = blockIdx.y, u0 = blockIdx.x * 64;
    int t = threadIdx.x;
    for (int i = t; i < 512; i += 256) m2s[i] = M2[i];
    #pragma unroll
    for (int it = 0; it < 8; ++it) {
        int f4 = t + 256 * it;
        int row = f4 >> 5;
        int col = (f4 & 31) * 4;
        float4 v = *(const float4*)(q + ((size_t)(b * U_N + u0 + row)) * D_N + col);
        qs[row][col] = v.x; qs[row][col + 1] = v.y; qs[row][col + 2] = v.z; qs[row][col + 3] = v.w;
    }
    __syncthreads();
    int ul = t >> 2, c = t & 3;
    float acc = 0.f;
    for (int d = 0; d < 128; ++d) acc += qs[ul][d] * m2s[d * 4 + c];
    qm[((size_t)(b * U_N + u0 + ul)) * 4 + c] = acc;
}

// ---------- K1: servers-in-lanes scoring. block = (b, 32-user chunk); lane owns 2 servers.
// Per-server running (max-key, exp-sum) in registers; partials stored, no atomics.
__global__ __launch_bounds__(256) void iter_score(
    const float* __restrict__ qk, const float* __restrict__ qm4,
    const float* __restrict__ nds, const unsigned* __restrict__ connU,
    const uint4* __restrict__ alloc3, const unsigned* __restrict__ rcArr,
    const unsigned* __restrict__ seenArr, const unsigned* __restrict__ fdm_,
    const float* __restrict__ capA, const float* __restrict__ invA,
    const float* __restrict__ usw, const float* __restrict__ sbp, const float* __restrict__ fdbp,
    ull* __restrict__ keypart, float* __restrict__ sumpart,
    const int* __restrict__ go, int iter) {
    if (go[iter] == 0) return;
    const int tid = threadIdx.x;
    const int b = blockIdx.x & 15;        // same-b blocks spaced 16 apart -> XCD-pinned by b%8
    const int ublk = blockIdx.x >> 4;     // 0..63, 32 users each
    const int u0 = ublk << 5;
    const int wid = tid >> 6, lane = tid & 63;
    const int s0 = wid * 128 + lane * 2;  // this thread's two servers: s0, s0+1
    const float w0 = usw[0], w1 = usw[1], w2 = usw[2], sb = sbp[0], fdb = fdbp[0];
    float ub[4];
    #pragma unroll
    for (int r = 0; r < 4; ++r)
        ub[r] = sb + w0 * (r * (1.0f / 3.0f)) + w1 * ((3 - r) * (1.0f / 3.0f)) + (r == 2 ? w2 : 0.0f);
    const int bs = b * S_N + s0;
    const float4 cap0 = ((const float4*)capA)[bs], cap1 = ((const float4*)capA)[bs + 1];
    const float4 iv0 = ((const float4*)invA)[bs], iv1 = ((const float4*)invA)[bs + 1];
    const float4 cr0 = make_float4(cap0.x * iv0.x, cap0.y * iv0.y, cap0.z * iv0.z, cap0.w * iv0.w);
    const float4 cr1 = make_float4(cap1.x * iv1.x, cap1.y * iv1.y, cap1.z * iv1.z, cap1.w * iv1.w);
    const unsigned f0 = fdm_[bs], f1 = fdm_[bs + 1];
    const unsigned us0 = (unsigned)s0, us1 = (unsigned)(s0 + 1);
    const int shift = s0 & 31;
    ull k0 = 0ULL, k1 = 0ULL;
    float e0 = 0.f, e1 = 0.f;
    const float* qkrow = qk + ((size_t)(b * U_N + u0)) * S_N + s0;
    const int gub = b * U_N + u0;
    #pragma unroll 4
    for (int uu = 0; uu < 32; ++uu) {
        const int gu = gub + uu;
        const float2 bl = *(const float2*)(qkrow + (size_t)uu * S_N);
        const float4 qmv = ((const float4*)qm4)[gu];   // wave-uniform -> scalar loads
        const float4 ndv = ((const float4*)nds)[gu];
        const unsigned rcu = rcArr[gu], snu = seenArr[gu];
        const uint4 al = alloc3[gu];
        const unsigned cw = connU[gu * 16 + (s0 >> 5)];
        const bool needm = rcu < 3u;
        const float add = ub[rcu & 3u];
        const bool aok0 = (al.x != us0) & (al.y != us0) & (al.z != us0);
        const bool aok1 = (al.x != us1) & (al.y != us1) & (al.z != us1);
        const bool ful0 = (cap0.x >= ndv.x) & (cap0.y >= ndv.y) & (cap0.z >= ndv.z) & (cap0.w >= ndv.w);
        const bool ful1 = (cap1.x >= ndv.x) & (cap1.y >= ndv.y) & (cap1.z >= ndv.z) & (cap1.w >= ndv.w);
        const bool el0 = (((cw >> shift) & 1u) != 0u) & needm & ful0 & aok0;
        const bool el1 = (((cw >> (shift + 1)) & 1u) != 0u) & needm & ful1 & aok1;
        const float fd0 = ((snu & f0) == 0u) ? fdb : 0.f;
        const float fd1 = ((snu & f1) == 0u) ? fdb : 0.f;
        const float lg0 = bl.x + qmv.x * cr0.x + qmv.y * cr0.y + qmv.z * cr0.z + qmv.w * cr0.w + add + fd0;
        const float lg1 = bl.y + qmv.x * cr1.x + qmv.y * cr1.y + qmv.z * cr1.z + qmv.w * cr1.w + add + fd1;
        const unsigned uinv = ~(unsigned)(u0 + uu);
        if (el0) {
            ull kk = ((ull)monof(lg0) << 32) | uinv;
            k0 = k0 > kk ? k0 : kk;
            e0 += __expf(lg0);
        }
        if (el1) {
            ull kk = ((ull)monof(lg1) << 32) | uinv;
            k1 = k1 > kk ? k1 : kk;
            e1 += __expf(lg1);
        }
    }
    const size_t p = (size_t)ublk * (B_N * S_N) + bs;
    keypart[p] = k0; keypart[p + 1] = k1;     // coalesced 1KB/wave
    sumpart[p] = e0; sumpart[p + 1] = e1;
}

// ---------- K2: reduce 64 partials per server, resolve proposals, flag chain ----------
__global__ __launch_bounds__(256) void iter_mid(
    const ull* __restrict__ keypart, const float* __restrict__ sumpart,
    const unsigned* __restrict__ fdm_, float* __restrict__ logp_prop,
    ull* __restrict__ ukey, unsigned* __restrict__ seen_gain,
    int* __restrict__ go, unsigned* __restrict__ any_valid, unsigned* __restrict__ done_cnt,
    const int* __restrict__ need_count, int iter) {
    if (go[iter] == 0) {
        if (blockIdx.x == 0 && threadIdx.x == 0) go[iter + 1] = 0;
        return;
    }
    const int i = blockIdx.x * 256 + threadIdx.x;  // b*512+s
    ull best = 0ULL;
    #pragma unroll 8
    for (int j = 0; j < 64; ++j) {
        ull k = keypart[(size_t)j * (B_N * S_N) + i];
        best = k > best ? k : best;
    }
    unsigned anyf = 0u;
    if (best != 0ULL) {
        float ssum = 0.f;
        #pragma unroll 8
        for (int j = 0; j < 64; ++j) ssum += sumpart[(size_t)j * (B_N * S_N) + i];
        const float mx = unmonof((unsigned)(best >> 32));
        const unsigned pu = ~(unsigned)best;   // winning user (ties -> smallest u)
        const int b = i >> 9, s = i & 511;
        logp_prop[i] = mx - __logf(ssum);      // == max - logsumexp
        ull pk = ((ull)monof(mx) << 32) | (~(unsigned)s);
        atomicMax(&ukey[b * U_N + pu], pk);
        atomicOr(&seen_gain[b * U_N + pu], fdm_[i]);
        anyf = 1u;
    }
    ull bal = __ballot(anyf != 0u);
    if ((threadIdx.x & 63) == 0 && bal != 0ULL) atomicOr(&any_valid[iter], 1u);
    __syncthreads();   // drains all waves' atomics (vmcnt) before done signal
    if (threadIdx.x == 0) {
        __threadfence();
        if (atomicAdd(&done_cnt[iter], 1u) == (unsigned)(gridDim.x - 1)) {
            go[iter + 1] = (any_valid[iter] != 0u && *need_count > 0) ? 1 : 0;
        }
    }
}

// ---------- K3: each user accepts its best proposer ----------
__global__ void iter_apply(const float* __restrict__ nds, const float* __restrict__ logp_prop,
                           ull* __restrict__ ukey, unsigned* __restrict__ seen_gain,
                           uint4* __restrict__ alloc3, unsigned* __restrict__ allocU,
                           unsigned* __restrict__ rcArr, unsigned* __restrict__ seenArr,
                           float* __restrict__ capA, float* __restrict__ logp,
                           const int* __restrict__ go, int* __restrict__ need_count, int iter) {
    if (go[iter] == 0) return;
    const int i = blockIdx.x * 256 + threadIdx.x;  // B*U
    const ull key = ukey[i];
    if (key == 0ULL) return;
    if (go[iter + 1] != 0) {
        const int b = i >> 11;
        const unsigned s = ~(unsigned)key;  // decode server
        const int bs = b * S_N + (int)s;
        uint4 al = alloc3[i];
        const unsigned r = rcArr[i];
        if (r == 0u) al.x = s; else if (r == 1u) al.y = s; else al.z = s;
        alloc3[i] = al;
        allocU[i * 16 + (s >> 5)] |= 1u << (s & 31u);
        const float4 nd = ((const float4*)nds)[i];
        float4 cv = ((float4*)capA)[bs];   // accepted servers are distinct per iter -> no race
        cv.x = fmaxf(cv.x - nd.x, 0.f); cv.y = fmaxf(cv.y - nd.y, 0.f);
        cv.z = fmaxf(cv.z - nd.z, 0.f); cv.w = fmaxf(cv.w - nd.w, 0.f);
        ((float4*)capA)[bs] = cv;
        rcArr[i] = r + 1u;
        if (r + 1u == 3u) atomicSub(need_count, 1);
        logp[i] += logp_prop[bs];
        seenArr[i] |= seen_gain[i];
    }
    ukey[i] = 0ULL;
    seen_gain[i] = 0u;
}

// ---------- finalize ----------
__global__ void finalize_logp(const float* __restrict__ logp, float* __restrict__ out) {
    int b = blockIdx.x, t = threadIdx.x;
    float s = 0.f;
    for (int u = t; u < U_N; u += 256) s += logp[b * U_N + u];
    #pragma unroll
    for (int m = 1; m < 64; m <<= 1) s += __shfl_xor(s, m, 64);
    __shared__ float r[4];
    if ((t & 63) == 0) r[t >> 6] = s;
    __syncthreads();
    if (t == 0) out[b] = r[0] + r[1] + r[2] + r[3];
}

__global__ void finalize_alloc(const unsigned* __restrict__ allocU, float* __restrict__ out) {
    int idx = blockIdx.x * 256 + threadIdx.x;  // B*U*S/4
    int bu = idx >> 7;
    int s4 = (idx & 127) * 4;
    unsigned w = allocU[bu * 16 + (s4 >> 5)];
    float4 o;
    o.x = ((w >> ((s4 + 0) & 31)) & 1u) ? 1.f : 0.f;
    o.y = ((w >> ((s4 + 1) & 31)) & 1u) ? 1.f : 0.f;
    o.z = ((w >> ((s4 + 2) & 31)) & 1u) ? 1.f : 0.f;
    o.w = ((w >> ((s4 + 3) & 31)) & 1u) ? 1.f : 0.f;
    *(float4*)(out + 16 + (size_t)bu * S_N + s4) = o;
}

__global__ void finalize_cap(const float* __restrict__ capA, float* __restrict__ out) {
    int i = blockIdx.x * 256 + threadIdx.x;
    if (i < B_N * S_N * 4) out[16 + (size_t)B_N * U_N * S_N + i] = capA[i];
}

extern "C" void kernel_launch(void* const* d_in, const int* in_sizes, int n_in,
                              void* d_out, int out_size, void* d_ws, size_t ws_size,
                              hipStream_t stream) {
    const float* user_enc = (const float*)d_in[0];
    const float* server_enc = (const float*)d_in[1];
    const float* users = (const float*)d_in[2];
    const float* servers = (const float*)d_in[3];
    const int* connect = (const int*)d_in[4];
    const int* fd_onehot = (const int*)d_in[5];
    const float* state_proj_w = (const float*)d_in[6];
    const float* state_proj_b = (const float*)d_in[7];
    const float* fd_bias = (const float*)d_in[8];
    const float* ptr_q_w = (const float*)d_in[9];
    const float* ptr_k_w = (const float*)d_in[10];
    const float* user_state_w = (const float*)d_in[11];
    const float* score_bias = (const float*)d_in[12];
    float* out = (float*)d_out;

    char* w = (char*)d_ws;
    float* qk = (float*)(w + 0);                           // (B,U,S) 67108864 B
    float* q = (float*)(w + 67108864);                     // (B,U,D) 16777216 B (dead after qk GEMM)
    ull* keypart = (ull*)(w + 67108864);                   // aliases q: (64,B*S) 4194304 B
    float* sumpart = (float*)(w + 71303168);               // aliases q: (64,B*S) 2097152 B
    float* base_k = (float*)(w + 83886080);                // (B,S,D) 4194304 B
    float* qm = (float*)(w + 88080384);                    // (B,U,4) 524288 B
    ull* connU = (ull*)(w + 88604672);                     // (B,U,8) 2097152 B
    unsigned* allocU = (unsigned*)(w + 90701824);          // (B,U,16) 2097152 B
    uint4* alloc3 = (uint4*)(w + 92798976);                // (B,U) 524288 B
    float* nds = (float*)(w + 93323264);                   // (B,U,4) 524288 B
    unsigned* fdm = (unsigned*)(w + 93847552);             // (B,S) 32768 B
    float* capA = (float*)(w + 93880320);                  // (B,S,4) 131072 B
    float* invA = (float*)(w + 94011392);                  // (B,S,4) 131072 B
    unsigned* rcArr = (unsigned*)(w + 94142464);           // (B,U) 131072 B
    unsigned* seenArr = (unsigned*)(w + 94273536);         // (B,U) 131072 B
    unsigned* seen_gain = (unsigned*)(w + 94404608);       // (B,U) 131072 B
    float* logp = (float*)(w + 94535680);                  // (B,U) 131072 B
    ull* ukey = (ull*)(w + 94666752);                      // (B,U) 262144 B
    float* logp_prop = (float*)(w + 94928896);             // (B,S) 32768 B
    float* M2 = (float*)(w + 94961664);                    // (D,4) 2048 B
    int* go = (int*)(w + 94963712);                        // 17 ints
    unsigned* any_valid = (unsigned*)(w + 94963712 + 128);
    unsigned* done_cnt = (unsigned*)(w + 94963712 + 192);
    int* need_count = (int*)(w + 94963712 + 256);

    init_state<<<2048, 256, 0, stream>>>(servers, users, fd_onehot, allocU, alloc3, rcArr, seenArr,
                                         seen_gain, logp, ukey, capA, invA, fdm, nds,
                                         go, any_valid, done_cnt, need_count);
    pack_connect<<<8192, 256, 0, stream>>>(connect, connU);
    // base_k = inv_sqrt_d * (server_enc + spb) @ ptr_k_w^T
    gemm_nt<true, true><<<dim3(8, 2, 16), 256, 0, stream>>>(server_enc, ptr_k_w, state_proj_b,
                                                            base_k, S_N, D_N, D_N, INV_SQRT_D);
    // q = user_enc @ ptr_q_w^T
    gemm_nt<true, false><<<dim3(32, 2, 16), 256, 0, stream>>>(user_enc, ptr_q_w, nullptr,
                                                              q, U_N, D_N, D_N, 1.0f);
    m2_kernel<<<1, 512, 0, stream>>>(ptr_k_w, state_proj_w, M2);
    qm_kernel<<<dim3(32, 16), 256, 0, stream>>>(q, M2, qm);
    // qk[b][u][s] = q[b][u] . base_k[b][s]   (scale folded into base_k)
    gemm_nt<false, false><<<dim3(32, 8, 16), 256, 0, stream>>>(q, base_k, nullptr,
                                                               qk, U_N, S_N, D_N, 1.0f);
    for (int it = 0; it < 16; ++it) {
        iter_score<<<1024, 256, 0, stream>>>(qk, qm, nds, (const unsigned*)connU, alloc3, rcArr,
                                             seenArr, fdm, capA, invA, user_state_w, score_bias,
                                             fd_bias, keypart, sumpart, go, it);
        iter_mid<<<32, 256, 0, stream>>>(keypart, sumpart, fdm, logp_prop, ukey, seen_gain,
                                         go, any_valid, done_cnt, need_count, it);
        iter_apply<<<128, 256, 0, stream>>>(nds, logp_prop, ukey, seen_gain, alloc3, allocU,
                                            rcArr, seenArr, capA, logp, go, need_count, it);
    }
    finalize_logp<<<16, 256, 0, stream>>>(logp, out);
    finalize_alloc<<<16384, 256, 0, stream>>>(allocU, out);
    finalize_cap<<<128, 256, 0, stream>>>(capA, out);
}